// Round 1
// baseline (6579.425 us; speedup 1.0000x reference)
//
#include <hip/hip_runtime.h>
#include <hip/hip_bf16.h>

#define NN 100000
#define EE 1600000
#define HH 128
#define NDIM 91
#define EDIM 20
#define BB 128
#define EPSF 1e-5f

// ---------------- embed: h = nf @ W + b  (N x 91 @ 91 x 128) ----------------
__global__ __launch_bounds__(256) void k_embed(const float* __restrict__ nf,
                                               const float* __restrict__ W,
                                               const float* __restrict__ b,
                                               float* __restrict__ h) {
  __shared__ float w_s[NDIM * HH];   // 46.6 KB
  __shared__ float b_s[HH];
  __shared__ float a_s[16 * 92];     // 5.9 KB (padded rows)
  for (int i = threadIdx.x; i < NDIM * HH; i += 256) w_s[i] = W[i];
  if (threadIdx.x < HH) b_s[threadIdx.x] = b[threadIdx.x];
  __syncthreads();
  int col = threadIdx.x & 127, rs = threadIdx.x >> 7;
  for (int base = blockIdx.x * 16; base < NN; base += gridDim.x * 16) {
    int nrows = min(16, NN - base);
    int tot = nrows * NDIM;
    for (int i = threadIdx.x; i < tot; i += 256) {
      int r = i / NDIM;
      a_s[r * 92 + (i - r * NDIM)] = nf[(size_t)base * NDIM + i];
    }
    __syncthreads();
    float acc[8];
#pragma unroll
    for (int r = 0; r < 8; r++) acc[r] = 0.f;
    for (int k = 0; k < NDIM; k++) {
      float w = w_s[k * HH + col];
#pragma unroll
      for (int r = 0; r < 8; r++) acc[r] += a_s[(rs * 8 + r) * 92 + k] * w;
    }
#pragma unroll
    for (int r = 0; r < 8; r++) {
      int row = base + rs * 8 + r;
      if (row < NN) h[(size_t)row * HH + col] = acc[r] + b_s[col];
    }
    __syncthreads();
  }
}

// ------------- node_mm: hs = h@Wsrc, hd = h@Wdst  (bf16 out) ---------------
// grid.y in 0..7: y<4 -> Wsrc->hs, else Wdst->hd; col offset (y&3)*64
__global__ __launch_bounds__(256) void k_node_mm(const float* __restrict__ h,
                                                 const float* __restrict__ Wsrc,
                                                 const float* __restrict__ Wdst,
                                                 __hip_bfloat16* __restrict__ hs,
                                                 __hip_bfloat16* __restrict__ hd) {
  __shared__ float w_s[HH * 64];   // 32 KB
  __shared__ float a_s[32 * HH];   // 16 KB
  const float* W = (blockIdx.y < 4) ? Wsrc : Wdst;
  __hip_bfloat16* out = (blockIdx.y < 4) ? hs : hd;
  int coff = (blockIdx.y & 3) * 64;
  for (int i = threadIdx.x; i < HH * 64; i += 256) {
    int k = i >> 6, c = i & 63;
    w_s[i] = W[k * 256 + coff + c];
  }
  __syncthreads();
  int col = threadIdx.x & 63, rs = threadIdx.x >> 6;  // rs in 0..3
  for (int base = blockIdx.x * 32; base < NN; base += gridDim.x * 32) {
    int nrows = min(32, NN - base);
    for (int i = threadIdx.x; i < nrows * HH; i += 256) a_s[i] = h[(size_t)base * HH + i];
    __syncthreads();
    float acc[8];
#pragma unroll
    for (int r = 0; r < 8; r++) acc[r] = 0.f;
    for (int k = 0; k < HH; k++) {
      float w = w_s[k * 64 + col];
#pragma unroll
      for (int r = 0; r < 8; r++) acc[r] += a_s[(rs * 8 + r) * HH + k] * w;
    }
#pragma unroll
    for (int r = 0; r < 8; r++) {
      int row = base + rs * 8 + r;
      if (row < NN) out[(size_t)row * 256 + coff + col] = __float2bfloat16(acc[r]);
    }
    __syncthreads();
  }
}

// ---- edge kernel: z = hs[src]+hd[dst]+e@We+b ; msg=sig(z1)*softplus(z2);
// ---- atomicAdd into agg[dst].  64-lane group per edge, 2 cols/lane.
__global__ __launch_bounds__(256) void k_edge(const __hip_bfloat16* __restrict__ hs,
                                              const __hip_bfloat16* __restrict__ hd,
                                              const float* __restrict__ ef,
                                              const int* __restrict__ src,
                                              const int* __restrict__ dst,
                                              const float* __restrict__ We,
                                              const float* __restrict__ bias,
                                              float* __restrict__ agg) {
  __shared__ float we_s[EDIM * 256];  // 20 KB
  __shared__ float b_s[256];
  for (int i = threadIdx.x; i < EDIM * 256; i += 256) we_s[i] = We[i];
  if (threadIdx.x < 256) b_s[threadIdx.x] = bias[threadIdx.x];
  __syncthreads();
  int lane = threadIdx.x & 63;
  int grp = threadIdx.x >> 6;
  int c2 = lane * 2;
  int slot = blockIdx.x * 4 + grp;
  int nslot = gridDim.x * 4;
  for (int e = slot; e < EE; e += nslot) {
    int s = src[e], d = dst[e];
    __hip_bfloat162 g0 = *(const __hip_bfloat162*)&hs[s * 256 + c2];
    __hip_bfloat162 g1 = *(const __hip_bfloat162*)&hs[s * 256 + 128 + c2];
    __hip_bfloat162 g2 = *(const __hip_bfloat162*)&hd[d * 256 + c2];
    __hip_bfloat162 g3 = *(const __hip_bfloat162*)&hd[d * 256 + 128 + c2];
    float za0 = b_s[c2] + __bfloat162float(g0.x) + __bfloat162float(g2.x);
    float za1 = b_s[c2 + 1] + __bfloat162float(g0.y) + __bfloat162float(g2.y);
    float zb0 = b_s[128 + c2] + __bfloat162float(g1.x) + __bfloat162float(g3.x);
    float zb1 = b_s[128 + c2 + 1] + __bfloat162float(g1.y) + __bfloat162float(g3.y);
#pragma unroll
    for (int k = 0; k < EDIM; k++) {
      float ev = ef[e * EDIM + k];
      const float2 w0 = *(const float2*)&we_s[k * 256 + c2];
      const float2 w1 = *(const float2*)&we_s[k * 256 + 128 + c2];
      za0 += ev * w0.x; za1 += ev * w0.y;
      zb0 += ev * w1.x; zb1 += ev * w1.y;
    }
    float sp0 = (zb0 > 0.f) ? (zb0 + log1pf(__expf(-zb0))) : log1pf(__expf(zb0));
    float sp1 = (zb1 > 0.f) ? (zb1 + log1pf(__expf(-zb1))) : log1pf(__expf(zb1));
    float m0 = sp0 / (1.f + __expf(-za0));
    float m1 = sp1 / (1.f + __expf(-za1));
    atomicAdd(&agg[d * HH + c2], m0);
    atomicAdd(&agg[d * HH + c2 + 1], m1);
  }
}

// ---------------- BN stats: per-column sum & sumsq over N rows --------------
__global__ __launch_bounds__(256) void k_bn_stats(const float* __restrict__ agg,
                                                  float* __restrict__ stats) {
  int col = threadIdx.x & 127, half = threadIdx.x >> 7;
  float s = 0.f, sq = 0.f;
  for (int row = blockIdx.x * 2 + half; row < NN; row += gridDim.x * 2) {
    float v = agg[(size_t)row * HH + col];
    s += v; sq += v * v;
  }
  __shared__ float ls[256], lq[256];
  ls[threadIdx.x] = s; lq[threadIdx.x] = sq;
  __syncthreads();
  if (half == 0) {
    atomicAdd(&stats[col], ls[col] + ls[col + 128]);
    atomicAdd(&stats[128 + col], lq[col] + lq[col + 128]);
  }
}

__global__ void k_bn_fin(float* stats, const float* __restrict__ gam,
                         const float* __restrict__ bet) {
  int c = threadIdx.x;
  if (c >= HH) return;
  float mean = stats[c] / (float)NN;
  float var = stats[HH + c] / (float)NN - mean * mean;
  float sc = rsqrtf(var + EPSF) * gam[c];
  stats[c] = sc;
  stats[HH + c] = bet[c] - mean * sc;
}

// ---------------- h = relu(h + agg*scale + shift) ---------------------------
__global__ __launch_bounds__(256) void k_update(float* __restrict__ h,
                                                const float* __restrict__ agg,
                                                const float* __restrict__ stats) {
  for (size_t i = (size_t)blockIdx.x * blockDim.x + threadIdx.x; i < (size_t)NN * HH;
       i += (size_t)gridDim.x * blockDim.x) {
    int c = (int)(i & 127);
    float v = h[i] + agg[i] * stats[c] + stats[128 + c];
    h[i] = fmaxf(v, 0.f);
  }
}

// ---------------- pooling: contiguous chunk per block, register acc ---------
__global__ void k_pool(const float* __restrict__ h, const int* __restrict__ batch,
                       float* __restrict__ g, float* __restrict__ gcnt) {
  int col = threadIdx.x;  // 128
  int chunk = (NN + gridDim.x - 1) / gridDim.x;
  int n0 = blockIdx.x * chunk, n1 = min(NN, n0 + chunk);
  if (n0 >= n1) return;
  int cur = batch[n0];
  float acc = 0.f, cnt = 0.f;
  for (int n = n0; n < n1; n++) {
    int bb = batch[n];
    if (bb != cur) {
      atomicAdd(&g[cur * HH + col], acc);
      if (col == 0) atomicAdd(&gcnt[cur], cnt);
      acc = 0.f; cnt = 0.f; cur = bb;
    }
    acc += h[(size_t)n * HH + col];
    cnt += 1.f;
  }
  atomicAdd(&g[cur * HH + col], acc);
  if (col == 0) atomicAdd(&gcnt[cur], cnt);
}

// ---------------- final head: mean-pool norm, fc1, BN, relu, out ------------
__global__ __launch_bounds__(256) void k_final(float* __restrict__ g,
                                               const float* __restrict__ gcnt,
                                               const float* __restrict__ fc1w,
                                               const float* __restrict__ fc1b,
                                               const float* __restrict__ gam,
                                               const float* __restrict__ bet,
                                               const float* __restrict__ ow,
                                               const float* __restrict__ ob,
                                               float* __restrict__ out) {
  __shared__ float w_s[HH * HH];  // 64 KB
  __shared__ float y_s[BB * HH];  // 64 KB
  __shared__ float ls[256], lq[256];
  for (int i = threadIdx.x; i < HH * HH; i += 256) w_s[i] = fc1w[i];
  for (int i = threadIdx.x; i < BB * HH; i += 256) {
    int r = i >> 7;
    g[i] = g[i] / fmaxf(gcnt[r], 1.f);
  }
  __syncthreads();
  int c = threadIdx.x & 127, h2 = threadIdx.x >> 7;
  for (int rr = 0; rr < 64; rr++) {
    int r = h2 * 64 + rr;
    float acc = fc1b[c];
    for (int k = 0; k < HH; k++) acc += g[r * HH + k] * w_s[k * HH + c];
    y_s[r * HH + c] = acc;
  }
  __syncthreads();
  float s = 0.f, sq = 0.f;
  for (int rr = 0; rr < 64; rr++) {
    float v = y_s[(h2 * 64 + rr) * HH + c];
    s += v; sq += v * v;
  }
  ls[threadIdx.x] = s; lq[threadIdx.x] = sq;
  __syncthreads();
  if (h2 == 0) {
    float ss = ls[c] + ls[c + 128], qq = lq[c] + lq[c + 128];
    float mean = ss / (float)BB, var = qq / (float)BB - mean * mean;
    float sc = rsqrtf(var + EPSF) * gam[c];
    ls[c] = sc;
    lq[c] = bet[c] - mean * sc;
  }
  __syncthreads();
  for (int rr = 0; rr < 64; rr++) {
    int r = h2 * 64 + rr;
    y_s[r * HH + c] = fmaxf(y_s[r * HH + c] * ls[c] + lq[c], 0.f);
  }
  __syncthreads();
  int r2 = threadIdx.x >> 1, hf = threadIdx.x & 1;
  float acc = 0.f;
  for (int k = hf * 64; k < hf * 64 + 64; k++) acc += y_s[r2 * HH + k] * ow[k];
  __syncthreads();
  ls[threadIdx.x] = acc;
  __syncthreads();
  if (hf == 0) out[r2] = ls[threadIdx.x] + ls[threadIdx.x + 1] + ob[0];
}

extern "C" void kernel_launch(void* const* d_in, const int* in_sizes, int n_in,
                              void* d_out, int out_size, void* d_ws, size_t ws_size,
                              hipStream_t stream) {
  (void)in_sizes; (void)n_in; (void)out_size; (void)ws_size;
  const float* node_feats = (const float*)d_in[0];
  const int* edge_index = (const int*)d_in[1];
  const float* edge_feats = (const float*)d_in[2];
  const int* batch = (const int*)d_in[3];
  const float* embed_w = (const float*)d_in[4];
  const float* embed_b = (const float*)d_in[5];
  const float* conv_wsrc = (const float*)d_in[6];
  const float* conv_wdst = (const float*)d_in[7];
  const float* conv_we = (const float*)d_in[8];
  const float* conv_b = (const float*)d_in[9];
  const float* bn_gamma = (const float*)d_in[10];
  const float* bn_beta = (const float*)d_in[11];
  const float* fc1_w = (const float*)d_in[12];
  const float* fc1_b = (const float*)d_in[13];
  const float* fc_bn_gamma = (const float*)d_in[14];
  const float* fc_bn_beta = (const float*)d_in[15];
  const float* out_w = (const float*)d_in[16];
  const float* out_b = (const float*)d_in[17];

  char* ws = (char*)d_ws;
  size_t o = 0;
  float* h = (float*)(ws + o);            o += (size_t)NN * HH * 4;       // 51.2 MB
  __hip_bfloat16* hs = (__hip_bfloat16*)(ws + o); o += (size_t)NN * 256 * 2;  // 51.2 MB
  __hip_bfloat16* hd = (__hip_bfloat16*)(ws + o); o += (size_t)NN * 256 * 2;  // 51.2 MB
  float* agg = (float*)(ws + o);          o += (size_t)NN * HH * 4;       // 51.2 MB
  float* stats = (float*)(ws + o);        o += 256 * 4;
  float* g = (float*)(ws + o);            o += (size_t)BB * HH * 4;
  float* gcnt = (float*)(ws + o);         o += BB * 4;

  k_embed<<<512, 256, 0, stream>>>(node_feats, embed_w, embed_b, h);

  for (int i = 0; i < 3; i++) {
    k_node_mm<<<dim3(256, 8), 256, 0, stream>>>(h, conv_wsrc + (size_t)i * HH * 256,
                                                conv_wdst + (size_t)i * HH * 256, hs, hd);
    hipMemsetAsync(agg, 0, (size_t)NN * HH * 4, stream);
    hipMemsetAsync(stats, 0, 256 * 4, stream);
    k_edge<<<4096, 256, 0, stream>>>(hs, hd, edge_feats, edge_index, edge_index + EE,
                                     conv_we + (size_t)i * EDIM * 256,
                                     conv_b + (size_t)i * 256, agg);
    k_bn_stats<<<1024, 256, 0, stream>>>(agg, stats);
    k_bn_fin<<<1, 128, 0, stream>>>(stats, bn_gamma + i * HH, bn_beta + i * HH);
    k_update<<<2048, 256, 0, stream>>>(h, agg, stats);
  }

  hipMemsetAsync(g, 0, (size_t)BB * HH * 4, stream);
  hipMemsetAsync(gcnt, 0, BB * 4, stream);
  k_pool<<<256, 128, 0, stream>>>(h, batch, g, gcnt);
  k_final<<<1, 256, 0, stream>>>(g, gcnt, fc1_w, fc1_b, fc_bn_gamma, fc_bn_beta,
                                 out_w, out_b, (float*)d_out);
}